// Round 8
// baseline (573.583 us; speedup 1.0000x reference)
//
#include <hip/hip_runtime.h>
#include <hip/hip_bf16.h>

typedef __bf16 bf16;
typedef __bf16 bf16x4 __attribute__((ext_vector_type(4)));
typedef __bf16 bf16x8 __attribute__((ext_vector_type(8)));
typedef float  f32x16 __attribute__((ext_vector_type(16)));

#define S_  1024
#define D_  64
#define BQ  256          // 256 queries per block; each 4-wave group covers all of them
#define BK  64
#define GKT 8            // k-tiles per group (group g: keys g*512 .. g*512+511)
#define QT  (S_/BQ)      // 4
#define LD  72           // bf16 stride: 144B rows, 16B-aligned

#define ZERO16 {0.f,0.f,0.f,0.f,0.f,0.f,0.f,0.f,0.f,0.f,0.f,0.f,0.f,0.f,0.f,0.f}

// S^T = K.Q^T ; O^T = V^T.P^T with 32x32x16 MFMA, n=64 queries per wave.
// A/B: m|n=lane&31, k=(lane>>5)*8+j.  C/D: col=lane&31, row=(reg&3)+8*(reg>>2)+4*(lane>>5).
// Key-permutation trick (round 7): V^T staged at rho(key) (swap bits 2<->3 of key
// index) makes the PV B-frag equal this lane's own exp'd QK registers. No P exchange.
// Round 8: intra-block K-split. Two 4-wave groups process disjoint key halves for
// the same 256 queries (no running max -> O,l are sum-decomposable); partials are
// combined through LDS in the epilogue. 16 waves/CU = 4/SIMD at VGPR<=128.
__global__ __launch_bounds__(512, 4)
void fa_fwd(const float* __restrict__ Q, const float* __restrict__ K,
            const float* __restrict__ V, const int* __restrict__ mask,
            float* __restrict__ O)
{
    // per group: [0] = ks[2][64][LD] dbuf, [1] = vt[2][64][LD] dbuf (18432 B each)
    __shared__ __align__(16) char smem[2][2][2 * BK * LD * sizeof(bf16)];

    const int tid  = threadIdx.x;
    const int g    = tid >> 8;          // k-group 0/1
    const int tl   = tid & 255;         // tid within group
    const int lane = tid & 63;
    const int w    = (tid >> 6) & 3;    // wave within group
    const int l32  = lane & 31;
    const int hi   = lane >> 5;

    bf16 (*ks)[BK][LD] = (bf16(*)[BK][LD])smem[g][0];
    bf16 (*vt)[BK][LD] = (bf16(*)[BK][LD])smem[g][1];

    // XCD swizzle: 4 q-tiles of one bh on one XCD (bid%8 round-robin)
    const int bid   = blockIdx.x;
    const int xcd   = bid & 7;
    const int rnd   = bid >> 3;                 // 0..63
    const int qtile = rnd & 3;
    const int bh    = ((rnd >> 2) << 3) | xcd;  // 0..127
    const int b     = bh >> 4;                  // H=16
    const size_t base = (size_t)bh * (S_ * D_);
    const int qW = qtile * BQ + w * 64;

    const float qscale = (mask[b] != 0) ? 0.0f : 0.1803368801111204f; // log2e/8

    // ---- Q B-fragments for 2 n-tiles: B[k=d][n=q] (both groups load same Q) ----
    bf16x8 qf[2][4];
    #pragma unroll
    for (int nt = 0; nt < 2; ++nt) {
        const float* qp = Q + base + (size_t)(qW + nt * 32 + l32) * D_ + hi * 8;
        #pragma unroll
        for (int kc = 0; kc < 4; ++kc) {
            float4 a = *(const float4*)(qp + kc * 16);
            float4 c = *(const float4*)(qp + kc * 16 + 4);
            bf16x8 f;
            f[0] = (bf16)(a.x * qscale); f[1] = (bf16)(a.y * qscale);
            f[2] = (bf16)(a.z * qscale); f[3] = (bf16)(a.w * qscale);
            f[4] = (bf16)(c.x * qscale); f[5] = (bf16)(c.y * qscale);
            f[6] = (bf16)(c.z * qscale); f[7] = (bf16)(c.w * qscale);
            qf[nt][kc] = f;
        }
    }

    f32x16 o[2][2];                  // [d-tile][n-tile]
    #pragma unroll
    for (int dm = 0; dm < 2; ++dm)
        #pragma unroll
        for (int nt = 0; nt < 2; ++nt) o[dm][nt] = (f32x16)ZERO16;
    float lsum[2] = {0.f, 0.f};

    const int vkq = (tl >> 2) & 15;     // V transpose: 4-key group (natural)
    const int vkp = (vkq & 12) | ((vkq & 1) << 1) | ((vkq >> 1) & 1); // rho
    const int vc4 = (tl & 3) + 4 * w;   // d-chunk
    const float4* gk = (const float4*)(K + base) + (size_t)g * GKT * 1024;
    const float4* gv = (const float4*)(V + base) + (size_t)g * GKT * 1024;

    // prologue: prefetch this group's tile 0
    float4 kr[4], vr[4];
    #pragma unroll
    for (int it = 0; it < 4; ++it) kr[it] = gk[it * 256 + tl];
    #pragma unroll
    for (int r = 0; r < 4; ++r)    vr[r]  = gv[(vkq * 4 + r) * 16 + vc4];

    auto mkpf = [&](const f32x16& sv, bf16x8& fA, bf16x8& fB, float& ls) {
        bf16x8 a, c;
        #pragma unroll
        for (int i = 0; i < 8; ++i) {
            float e0 = __builtin_amdgcn_exp2f(sv[i]);
            float e1 = __builtin_amdgcn_exp2f(sv[8 + i]);
            ls += e0 + e1;
            a[i] = (bf16)e0;
            c[i] = (bf16)e1;
        }
        fA = a; fB = c;
    };

    for (int kt = 0; kt < GKT; ++kt) {
        bf16 (*ksb)[LD] = ks[kt & 1];
        bf16 (*vtb)[LD] = vt[kt & 1];

        // ---- stage K tile from regs (natural key rows) ----
        #pragma unroll
        for (int it = 0; it < 4; ++it) {
            int i = it * 256 + tl;
            int row = i >> 4, c4 = i & 15;
            bf16x4 hk = {(bf16)kr[it].x, (bf16)kr[it].y, (bf16)kr[it].z, (bf16)kr[it].w};
            *(bf16x4*)&ksb[row][c4 * 4] = hk;
        }
        // ---- stage V^T from regs at rho-permuted columns ----
        {
            bf16x4 t0 = {(bf16)vr[0].x, (bf16)vr[1].x, (bf16)vr[2].x, (bf16)vr[3].x};
            bf16x4 t1 = {(bf16)vr[0].y, (bf16)vr[1].y, (bf16)vr[2].y, (bf16)vr[3].y};
            bf16x4 t2 = {(bf16)vr[0].z, (bf16)vr[1].z, (bf16)vr[2].z, (bf16)vr[3].z};
            bf16x4 t3 = {(bf16)vr[0].w, (bf16)vr[1].w, (bf16)vr[2].w, (bf16)vr[3].w};
            *(bf16x4*)&vtb[vc4 * 4 + 0][vkp * 4] = t0;
            *(bf16x4*)&vtb[vc4 * 4 + 1][vkp * 4] = t1;
            *(bf16x4*)&vtb[vc4 * 4 + 2][vkp * 4] = t2;
            *(bf16x4*)&vtb[vc4 * 4 + 3][vkp * 4] = t3;
        }
        // ---- prefetch next tile ----
        {
            int ktn = (kt + 1 < GKT) ? (kt + 1) : kt;
            #pragma unroll
            for (int it = 0; it < 4; ++it) kr[it] = gk[ktn * 1024 + it * 256 + tl];
            #pragma unroll
            for (int r = 0; r < 4; ++r)    vr[r]  = gv[ktn * 1024 + (vkq * 4 + r) * 16 + vc4];
        }
        __syncthreads();   // both groups: single barrier per tile (dbuf-safe)

        // ---- S^T = K.Q^T : 2 m-tiles (keys) x 2 n-tiles (queries) ----
        f32x16 s00 = ZERO16, s01 = ZERO16, s10 = ZERO16, s11 = ZERO16;
        #pragma unroll
        for (int kc = 0; kc < 4; ++kc) {
            bf16x8 k0 = *(const bf16x8*)&ksb[l32][kc * 16 + hi * 8];
            bf16x8 k1 = *(const bf16x8*)&ksb[32 + l32][kc * 16 + hi * 8];
            s00 = __builtin_amdgcn_mfma_f32_32x32x16_bf16(k0, qf[0][kc], s00, 0, 0, 0);
            s01 = __builtin_amdgcn_mfma_f32_32x32x16_bf16(k0, qf[1][kc], s01, 0, 0, 0);
            s10 = __builtin_amdgcn_mfma_f32_32x32x16_bf16(k1, qf[0][kc], s10, 0, 0, 0);
            s11 = __builtin_amdgcn_mfma_f32_32x32x16_bf16(k1, qf[1][kc], s11, 0, 0, 0);
        }

        // ---- exp -> PV B-frags, all in-lane (key-permutation trick) ----
        bf16x8 pf[4][2];                 // [kc][nt]
        mkpf(s00, pf[0][0], pf[1][0], lsum[0]);
        mkpf(s01, pf[0][1], pf[1][1], lsum[1]);
        mkpf(s10, pf[2][0], pf[3][0], lsum[0]);
        mkpf(s11, pf[2][1], pf[3][1], lsum[1]);

        // ---- O^T += V^T.P^T ----
        #pragma unroll
        for (int kc = 0; kc < 4; ++kc) {
            bf16x8 v0 = *(const bf16x8*)&vtb[l32][kc * 16 + hi * 8];
            bf16x8 v1 = *(const bf16x8*)&vtb[32 + l32][kc * 16 + hi * 8];
            o[0][0] = __builtin_amdgcn_mfma_f32_32x32x16_bf16(v0, pf[kc][0], o[0][0], 0, 0, 0);
            o[0][1] = __builtin_amdgcn_mfma_f32_32x32x16_bf16(v0, pf[kc][1], o[0][1], 0, 0, 0);
            o[1][0] = __builtin_amdgcn_mfma_f32_32x32x16_bf16(v1, pf[kc][0], o[1][0], 0, 0, 0);
            o[1][1] = __builtin_amdgcn_mfma_f32_32x32x16_bf16(v1, pf[kc][1], o[1][1], 0, 0, 0);
        }
    }

    // ---- per-group l reduction across key halves (hi split) ----
    float lv[2];
    #pragma unroll
    for (int nt = 0; nt < 2; ++nt)
        lv[nt] = lsum[nt] + __shfl_xor(lsum[nt], 32);

    // ---- cross-group combine through LDS ----
    __syncthreads();                       // all tile-buffer reads complete
    float* oex = (float*)smem;             // [16 chunks][256 threads][4 f32] = 64 KB
    float* lex = oex + 16 * 256 * 4;       // [256 q] partial l from group 1

    if (g == 1) {
        #pragma unroll
        for (int dm = 0; dm < 2; ++dm)
            #pragma unroll
            for (int nt = 0; nt < 2; ++nt)
                #pragma unroll
                for (int c = 0; c < 4; ++c) {
                    int chunk = (dm * 2 + nt) * 4 + c;
                    float4 v = { o[dm][nt][c * 4 + 0], o[dm][nt][c * 4 + 1],
                                 o[dm][nt][c * 4 + 2], o[dm][nt][c * 4 + 3] };
                    *(float4*)&oex[(chunk * 256 + tl) * 4] = v;
                }
        if (hi == 0) {
            lex[w * 64 + l32]      = lv[0];   // q_local = w*64 + nt*32 + l32
            lex[w * 64 + 32 + l32] = lv[1];
        }
    }
    __syncthreads();

    if (g == 0) {
        #pragma unroll
        for (int nt = 0; nt < 2; ++nt) {
            float lt  = lv[nt] + lex[w * 64 + nt * 32 + l32];
            float inv = 1.0f / lt;
            float* op = O + base + (size_t)(qW + nt * 32 + l32) * D_ + hi * 4;
            #pragma unroll
            for (int gg = 0; gg < 4; ++gg) {
                float4 p0 = *(float4*)&oex[(((0 * 2 + nt) * 4 + gg) * 256 + tl) * 4];
                float4 p1 = *(float4*)&oex[(((1 * 2 + nt) * 4 + gg) * 256 + tl) * 4];
                float4 a = { (o[0][nt][gg * 4 + 0] + p0.x) * inv,
                             (o[0][nt][gg * 4 + 1] + p0.y) * inv,
                             (o[0][nt][gg * 4 + 2] + p0.z) * inv,
                             (o[0][nt][gg * 4 + 3] + p0.w) * inv };
                *(float4*)(op + gg * 8) = a;            // d = 4hi + 8g + r
                float4 c = { (o[1][nt][gg * 4 + 0] + p1.x) * inv,
                             (o[1][nt][gg * 4 + 1] + p1.y) * inv,
                             (o[1][nt][gg * 4 + 2] + p1.z) * inv,
                             (o[1][nt][gg * 4 + 3] + p1.w) * inv };
                *(float4*)(op + 32 + gg * 8) = c;       // d = 32 + 4hi + 8g + r
            }
        }
    }
}

extern "C" void kernel_launch(void* const* d_in, const int* in_sizes, int n_in,
                              void* d_out, int out_size, void* d_ws, size_t ws_size,
                              hipStream_t stream)
{
    const float* Q    = (const float*)d_in[0];
    const float* K    = (const float*)d_in[1];
    const float* V    = (const float*)d_in[2];
    const int*   mask = (const int*)d_in[3];
    float*       O    = (float*)d_out;

    dim3 grid(8 * 16 * QT);   // 512 blocks x 512 threads = 2 blocks/CU, 16 waves/CU
    fa_fwd<<<grid, 512, 0, stream>>>(Q, K, V, mask, O);
}